// Round 18
// baseline (157.441 us; speedup 1.0000x reference)
//
#include <hip/hip_runtime.h>
#include <math.h>

constexpr int TLEN = 512;
constexpr int CDIM = 64;
constexpr int BDIM = 2;
constexpr int LOOPS_HK = 32;   // DIAGNOSTIC
constexpr int LOOPS_AT = 16;   // DIAGNOSTIC

// Phase 1: hkt4[(b*16+c4)*512 + t] = float4-over-c of hk[b,t,c]. (R15 + loop)
__global__ __launch_bounds__(256) void hk_kernel(
    const float* __restrict__ x, const float* __restrict__ pos,
    const float* __restrict__ W1, float4* __restrict__ hkt4_in)
{
    const int tid = threadIdx.x;
    const int r0g = blockIdx.x * 4;
    const int b   = r0g >> 9;
    const int t0  = r0g & (TLEN - 1);

    __shared__ float4 wk_s[64 * 32];
    __shared__ alignas(16) float x1s[4][128];
    __shared__ float hks[CDIM][5];

    const float4* W1f4 = (const float4*)W1;
    #pragma unroll
    for (int m = tid; m < 64 * 32; m += 256) {
        const int c = m >> 5, e4 = m & 31;
        wk_s[c * 32 + (e4 ^ (c & 31))] = W1f4[c * 64 + e4];
    }
    #pragma unroll
    for (int e = tid; e < 4 * 128; e += 256) {
        const int r4 = e >> 7, d = e & 127;
        const int grow = r0g + r4;
        const int tt = grow & (TLEN - 1);
        x1s[r4][d] = (d < CDIM) ? pos[tt * CDIM + d]
                                : x[grow * CDIM + (d - CDIM)];
    }
    __syncthreads();

    for (int it = 0; it < LOOPS_HK; ++it) {
        float4* hkt4 = hkt4_in;
        asm volatile("" : "+v"(hkt4));
        float zero = 0.f;
        asm volatile("" : "+v"(zero));
        {
            const int sub = tid >> 6, c = tid & 63;
            const float4* xv = (const float4*)x1s[sub];
            const float4* wb = wk_s + c * 32;
            const int sw = c & 31;
            float4 a = make_float4(zero, zero, zero, zero);
            #pragma unroll
            for (int d4 = 0; d4 < 32; ++d4) {
                const float4 xx = xv[d4];
                const float4 ww = wb[d4 ^ sw];
                a.x = fmaf(xx.x, ww.x, a.x); a.y = fmaf(xx.y, ww.y, a.y);
                a.z = fmaf(xx.z, ww.z, a.z); a.w = fmaf(xx.w, ww.w, a.w);
            }
            hks[c][sub] = (a.x + a.y) + (a.z + a.w);
        }
        __syncthreads();
        if (tid < 64) {
            const int c4 = tid >> 2, tl = tid & 3;
            const float4 v = make_float4(hks[c4*4+0][tl], hks[c4*4+1][tl],
                                         hks[c4*4+2][tl], hks[c4*4+3][tl]);
            hkt4[(b * 16 + c4) * TLEN + t0 + tl] = v;
        }
        __syncthreads();
    }
}

// Phase 2: R15 attn verbatim + LOOPS_AT replay of {hq, score, PV, epilogue}.
__global__ __launch_bounds__(512, 4) void attn_kernel(
    const float* __restrict__ x,  const float* __restrict__ pos,
    const float* __restrict__ W1, const float* __restrict__ b1,
    const float* __restrict__ W2, const float* __restrict__ b2,
    const float* __restrict__ Wv, const float4* __restrict__ hkt4_in,
    float* __restrict__ out)
{
    const int tid = threadIdx.x;
    const int idx = blockIdx.x;
    const int b   = idx & 1;
    const int p   = idx >> 1;
    int rr[2];
    rr[0] = p; rr[1] = (TLEN - 1) - p;

    __shared__ float4 wq_s[64 * 32];
    __shared__ float4 wv_s[64 * 16];
    __shared__ alignas(16) float x1s[2][128];
    __shared__ float hqp[2][CDIM][4];
    __shared__ alignas(16) float hq_sf[2][CDIM];
    __shared__ float4 w24_s[16];
    __shared__ alignas(16) float pS[2][TLEN];
    __shared__ float2 wreds[8];
    __shared__ float pvs[2][8][CDIM];
    __shared__ alignas(16) float o_s[2][CDIM];

    const float4* W1f4 = (const float4*)W1;
    #pragma unroll
    for (int m = tid; m < 64 * 32; m += 512) {
        const int c = m >> 5, e4 = m & 31;
        wq_s[c * 32 + (e4 ^ (c & 31))] = W1f4[c * 64 + 32 + e4];
    }
    const float4* Wvf4 = (const float4*)Wv;
    #pragma unroll
    for (int m = tid; m < 64 * 16; m += 512) {
        const int hh = m >> 4, e4 = m & 15;
        wv_s[hh * 16 + (e4 ^ (hh & 15))] = Wvf4[hh * 16 + e4];
    }
    if (tid < 256) {
        const int rp = tid >> 7, d = tid & 127;
        const int i  = rr[rp];
        x1s[rp][d] = (d < CDIM) ? pos[i * CDIM + d]
                                : x[(b * TLEN + i) * CDIM + (d - CDIM)];
    } else if (tid < 272) {
        w24_s[tid - 256] = ((const float4*)W2)[tid - 256];
    }
    __syncthreads();

    const float b2v = b2[0];
    const int j = tid;
    const int w = tid >> 6;

    for (int it = 0; it < LOOPS_AT; ++it) {
        const float4* hk4b = hkt4_in + b * 16 * TLEN;
        const float* xh0 = x + b * TLEN * CDIM;
        asm volatile("" : "+v"(hk4b));
        asm volatile("" : "+v"(xh0));
        float zero = 0.f;
        asm volatile("" : "+v"(zero));

        // ---- hq phase ----
        {
            const int k = tid >> 8, part = (tid >> 6) & 3, c = tid & 63;
            const float4* xv = ((const float4*)x1s[k]) + part * 8;
            const float4* wb = wq_s + c * 32;
            const int sw = c & 31;
            float4 a = make_float4(zero, zero, zero, zero);
            #pragma unroll
            for (int d4 = 0; d4 < 8; ++d4) {
                const float4 xx = xv[d4];
                const float4 ww = wb[(part * 8 + d4) ^ sw];
                a.x = fmaf(xx.x, ww.x, a.x); a.y = fmaf(xx.y, ww.y, a.y);
                a.z = fmaf(xx.z, ww.z, a.z); a.w = fmaf(xx.w, ww.w, a.w);
            }
            hqp[k][c][part] = (a.x + a.y) + (a.z + a.w);
        }
        __syncthreads();
        if (tid < 128) {
            const int k = tid >> 6, c = tid & 63;
            hq_sf[k][c] = hqp[k][c][0] + hqp[k][c][1] + hqp[k][c][2]
                        + hqp[k][c][3] + b1[c];
        }
        __syncthreads();

        // ---- scores -> exp -> pS + per-wave sums (no max) ----
        float swv[2];
        #pragma unroll
        for (int k = 0; k < 2; ++k) {
            const int rk = rr[k];
            if ((w << 6) <= rk) {
                const float4* hq4 = (const float4*)hq_sf[k];
                float4 acc = make_float4(zero, zero, zero, zero);
                #pragma unroll
                for (int c4 = 0; c4 < 16; ++c4) {
                    const float4 kk = hk4b[c4 * TLEN + j];
                    const float4 qq = hq4[c4];
                    const float4 w2v = w24_s[c4];
                    acc.x = fmaf(fmaxf(kk.x + qq.x, 0.f), w2v.x, acc.x);
                    acc.y = fmaf(fmaxf(kk.y + qq.y, 0.f), w2v.y, acc.y);
                    acc.z = fmaf(fmaxf(kk.z + qq.z, 0.f), w2v.z, acc.z);
                    acc.w = fmaf(fmaxf(kk.w + qq.w, 0.f), w2v.w, acc.w);
                }
                const bool vld = (j <= rk);
                const float sv = ((acc.x + acc.y) + (acc.z + acc.w) + b2v)
                                 * 0.125f;
                const float pt = vld ? __expf(sv) : 0.f;
                pS[k][j] = pt;
                float sm = pt;
                #pragma unroll
                for (int off = 32; off > 0; off >>= 1)
                    sm += __shfl_xor(sm, off);
                swv[k] = sm;
            } else {
                swv[k] = 0.f;
            }
        }
        if ((tid & 63) == 0) wreds[w] = make_float2(swv[0], swv[1]);
        __syncthreads();

        // ---- PV ----
        const int h = tid & 63;
        const int g = w;
        const float* xh = xh0 + h;
        const int nj4 = (rr[1] >> 2) + 1;
        float4 a0 = make_float4(zero, zero, zero, zero);
        float4 a1 = a0;
        for (int j4 = g; j4 < nj4; j4 += 8) {
            const int j0 = j4 * 4;
            const float4 p1v = ((const float4*)pS[1])[j4];
            const float x0 = xh[j0 * CDIM];
            const float x1 = xh[(j0 + 1) * CDIM];
            const float x2 = xh[(j0 + 2) * CDIM];
            const float x3 = xh[(j0 + 3) * CDIM];
            a1.x = fmaf(p1v.x, x0, a1.x); a1.y = fmaf(p1v.y, x1, a1.y);
            a1.z = fmaf(p1v.z, x2, a1.z); a1.w = fmaf(p1v.w, x3, a1.w);
            if (j0 <= rr[0]) {
                const float4 p0v = ((const float4*)pS[0])[j4];
                a0.x = fmaf(p0v.x, x0, a0.x); a0.y = fmaf(p0v.y, x1, a0.y);
                a0.z = fmaf(p0v.z, x2, a0.z); a0.w = fmaf(p0v.w, x3, a0.w);
            }
        }
        pvs[0][g][h] = (a0.x + a0.y) + (a0.z + a0.w);
        pvs[1][g][h] = (a1.x + a1.y) + (a1.z + a1.w);
        __syncthreads();
        if (tid < 128) {
            const int k = tid >> 6, hh = tid & 63;
            float o = pvs[k][0][hh];
            #pragma unroll
            for (int ww = 1; ww < 8; ++ww) o += pvs[k][ww][hh];
            float gsum = 0.f;
            #pragma unroll
            for (int ww = 0; ww < 8; ++ww)
                gsum += (k == 0) ? wreds[ww].x : wreds[ww].y;
            o_s[k][hh] = o / gsum;
        }
        __syncthreads();
        if (tid < 128) {
            const int k = tid >> 6, hh = tid & 63;
            const float4* wb = wv_s + hh * 16;
            const int sw = hh & 15;
            const float4* o4 = (const float4*)o_s[k];
            float4 a = make_float4(zero, zero, zero, zero);
            #pragma unroll
            for (int c4 = 0; c4 < 16; ++c4) {
                const float4 wwv = wb[c4 ^ sw];
                const float4 oo = o4[c4];
                a.x = fmaf(oo.x, wwv.x, a.x); a.y = fmaf(oo.y, wwv.y, a.y);
                a.z = fmaf(oo.z, wwv.z, a.z); a.w = fmaf(oo.w, wwv.w, a.w);
            }
            out[(b * TLEN + rr[k]) * CDIM + hh] = (a.x + a.y) + (a.z + a.w);
        }
        __syncthreads();
    }
}

extern "C" void kernel_launch(void* const* d_in, const int* in_sizes, int n_in,
                              void* d_out, int out_size, void* d_ws, size_t ws_size,
                              hipStream_t stream)
{
    const float* x   = (const float*)d_in[0];
    const float* pos = (const float*)d_in[1];
    const float* W1  = (const float*)d_in[2];
    const float* b1  = (const float*)d_in[3];
    const float* W2  = (const float*)d_in[4];
    const float* b2  = (const float*)d_in[5];
    const float* Wv  = (const float*)d_in[6];
    float* out = (float*)d_out;

    float4* hkt4 = (float4*)d_ws;

    hk_kernel<<<BDIM * TLEN / 4, 256, 0, stream>>>(x, pos, W1, hkt4);
    attn_kernel<<<BDIM * TLEN / 2, 512, 0, stream>>>(x, pos, W1, b1, W2, b2, Wv,
                                                     hkt4, out);
}

// Round 19
// 19.072 us; speedup vs baseline: 8.2550x; 8.2550x over previous
//
#include <hip/hip_runtime.h>
#include <math.h>

constexpr int TLEN = 512;
constexpr int CDIM = 64;
constexpr int BDIM = 2;

// Phase 1: hkt4[(b*16+c4)*512 + t] = float4-over-c of hk[b,t,c]. (R15, unchanged)
__global__ __launch_bounds__(256) void hk_kernel(
    const float* __restrict__ x, const float* __restrict__ pos,
    const float* __restrict__ W1, float4* __restrict__ hkt4)
{
    const int tid = threadIdx.x;
    const int r0g = blockIdx.x * 4;
    const int b   = r0g >> 9;
    const int t0  = r0g & (TLEN - 1);

    __shared__ float4 wk_s[64 * 32];          // 32 KiB swizzled Wk
    __shared__ alignas(16) float x1s[4][128];
    __shared__ float hks[CDIM][5];            // +1 pad

    const float4* W1f4 = (const float4*)W1;
    #pragma unroll
    for (int m = tid; m < 64 * 32; m += 256) {
        const int c = m >> 5, e4 = m & 31;
        wk_s[c * 32 + (e4 ^ (c & 31))] = W1f4[c * 64 + e4];
    }
    #pragma unroll
    for (int e = tid; e < 4 * 128; e += 256) {
        const int r4 = e >> 7, d = e & 127;
        const int grow = r0g + r4;
        const int tt = grow & (TLEN - 1);
        x1s[r4][d] = (d < CDIM) ? pos[tt * CDIM + d]
                                : x[grow * CDIM + (d - CDIM)];
    }
    __syncthreads();

    {
        const int sub = tid >> 6, c = tid & 63;
        const float4* xv = (const float4*)x1s[sub];
        const float4* wb = wk_s + c * 32;
        const int sw = c & 31;
        float4 a = make_float4(0.f, 0.f, 0.f, 0.f);
        #pragma unroll
        for (int d4 = 0; d4 < 32; ++d4) {
            const float4 xx = xv[d4];
            const float4 ww = wb[d4 ^ sw];
            a.x = fmaf(xx.x, ww.x, a.x); a.y = fmaf(xx.y, ww.y, a.y);
            a.z = fmaf(xx.z, ww.z, a.z); a.w = fmaf(xx.w, ww.w, a.w);
        }
        hks[c][sub] = (a.x + a.y) + (a.z + a.w);
    }
    __syncthreads();

    if (tid < 64) {
        const int c4 = tid >> 2, tl = tid & 3;
        const float4 v = make_float4(hks[c4 * 4 + 0][tl], hks[c4 * 4 + 1][tl],
                                     hks[c4 * 4 + 2][tl], hks[c4 * 4 + 3][tl]);
        hkt4[(b * 16 + c4) * TLEN + t0 + tl] = v;
    }
}

// Phase 2: R15 structure, ONE change: balanced score assignment — each
// thread computes exactly one (row, col) dot; thread 511 takes the 513th.
__global__ __launch_bounds__(512, 4) void attn_kernel(
    const float* __restrict__ x,  const float* __restrict__ pos,
    const float* __restrict__ W1, const float* __restrict__ b1,
    const float* __restrict__ W2, const float* __restrict__ b2,
    const float* __restrict__ Wv, const float4* __restrict__ hkt4,
    float* __restrict__ out)
{
    const int tid = threadIdx.x;
    const int idx = blockIdx.x;               // 0..511
    const int b   = idx & 1;
    const int p   = idx >> 1;                 // 0..255
    int rr[2];
    rr[0] = p; rr[1] = (TLEN - 1) - p;        // rr[1] >= 256 > rr[0]

    __shared__ float4 wq_s[64 * 32];          // 32 KiB swizzled Wq
    __shared__ float4 wv_s[64 * 16];          // 16 KiB swizzled Wv
    __shared__ alignas(16) float x1s[2][128];
    __shared__ float hqp[2][CDIM][4];
    __shared__ alignas(16) float hq_sf[2][CDIM];
    __shared__ float4 w24_s[16];
    __shared__ alignas(16) float pS[2][TLEN];
    __shared__ float2 wreds[8];               // per-wave exp-sums (2 rows)
    __shared__ float pvs[2][8][CDIM];
    __shared__ alignas(16) float o_s[2][CDIM];

    // ---- stage Wq, Wv (coalesced + swizzled), x1 for 2 rows, W2 ----
    const float4* W1f4 = (const float4*)W1;
    #pragma unroll
    for (int m = tid; m < 64 * 32; m += 512) {
        const int c = m >> 5, e4 = m & 31;
        wq_s[c * 32 + (e4 ^ (c & 31))] = W1f4[c * 64 + 32 + e4];
    }
    const float4* Wvf4 = (const float4*)Wv;
    #pragma unroll
    for (int m = tid; m < 64 * 16; m += 512) {
        const int hh = m >> 4, e4 = m & 15;
        wv_s[hh * 16 + (e4 ^ (hh & 15))] = Wvf4[hh * 16 + e4];
    }
    if (tid < 256) {
        const int rp = tid >> 7, d = tid & 127;
        const int i  = rr[rp];
        x1s[rp][d] = (d < CDIM) ? pos[i * CDIM + d]
                                : x[(b * TLEN + i) * CDIM + (d - CDIM)];
    } else if (tid < 272) {
        w24_s[tid - 256] = ((const float4*)W2)[tid - 256];
    }
    __syncthreads();

    // ---- hq: thread -> (row k, quarter part, c); 8-f4 dots (R15) ----
    {
        const int k = tid >> 8, part = (tid >> 6) & 3, c = tid & 63;
        const float4* xv = ((const float4*)x1s[k]) + part * 8;
        const float4* wb = wq_s + c * 32;
        const int sw = c & 31;
        float4 a = make_float4(0.f, 0.f, 0.f, 0.f);
        #pragma unroll
        for (int d4 = 0; d4 < 8; ++d4) {
            const float4 xx = xv[d4];
            const float4 ww = wb[(part * 8 + d4) ^ sw];
            a.x = fmaf(xx.x, ww.x, a.x); a.y = fmaf(xx.y, ww.y, a.y);
            a.z = fmaf(xx.z, ww.z, a.z); a.w = fmaf(xx.w, ww.w, a.w);
        }
        hqp[k][c][part] = (a.x + a.y) + (a.z + a.w);
    }
    __syncthreads();
    if (tid < 128) {
        const int k = tid >> 6, c = tid & 63;
        hq_sf[k][c] = hqp[k][c][0] + hqp[k][c][1] + hqp[k][c][2]
                    + hqp[k][c][3] + b1[c];
    }
    __syncthreads();

    // ---- balanced scores: one dot per thread (no causal waste) ----
    const float b2v = b2[0];
    const float4* hk4b = hkt4 + b * 16 * TLEN;
    const int j = tid;
    const int w = tid >> 6;
    const int n1 = TLEN - p;                  // cols in row 1 (= rr[1]+1)
    const bool isR1 = (j < n1);
    const int myrow = isR1 ? 1 : 0;
    const int mycol = isR1 ? j : j - n1;      // valid: col <= row always

    float pt;
    {
        const float4* hq4 = (const float4*)hq_sf[myrow];
        float4 acc = make_float4(0.f, 0.f, 0.f, 0.f);
        #pragma unroll
        for (int c4 = 0; c4 < 16; ++c4) {
            const float4 kk = hk4b[c4 * TLEN + mycol];
            const float4 qq = hq4[c4];
            const float4 ww = w24_s[c4];
            acc.x = fmaf(fmaxf(kk.x + qq.x, 0.f), ww.x, acc.x);
            acc.y = fmaf(fmaxf(kk.y + qq.y, 0.f), ww.y, acc.y);
            acc.z = fmaf(fmaxf(kk.z + qq.z, 0.f), ww.z, acc.z);
            acc.w = fmaf(fmaxf(kk.w + qq.w, 0.f), ww.w, acc.w);
        }
        const float sv = ((acc.x + acc.y) + (acc.z + acc.w) + b2v) * 0.125f;
        pt = __expf(sv);                      // bounded scores, no max needed
    }
    pS[myrow][mycol] = pt;

    float ptx = 0.f;                          // 513th unit: (row 0, col p)
    if (j == TLEN - 1) {
        const float4* hq4 = (const float4*)hq_sf[0];
        float4 acc = make_float4(0.f, 0.f, 0.f, 0.f);
        #pragma unroll
        for (int c4 = 0; c4 < 16; ++c4) {
            const float4 kk = hk4b[c4 * TLEN + p];
            const float4 qq = hq4[c4];
            const float4 ww = w24_s[c4];
            acc.x = fmaf(fmaxf(kk.x + qq.x, 0.f), ww.x, acc.x);
            acc.y = fmaf(fmaxf(kk.y + qq.y, 0.f), ww.y, acc.y);
            acc.z = fmaf(fmaxf(kk.z + qq.z, 0.f), ww.z, acc.z);
            acc.w = fmaf(fmaxf(kk.w + qq.w, 0.f), ww.w, acc.w);
        }
        const float sv = ((acc.x + acc.y) + (acc.z + acc.w) + b2v) * 0.125f;
        ptx = __expf(sv);
        pS[0][p] = ptx;
    }
    // zero the float4 tails PV may touch: row0 cols p+1..p+3, row1 rr1+1..+3
    if (j < 3) {
        if (p + 1 + j < TLEN)     pS[0][p + 1 + j] = 0.f;
        if (rr[1] + 1 + j < TLEN) pS[1][rr[1] + 1 + j] = 0.f;
    }

    // per-wave sums (each thread contributes to its own row)
    float c0 = isR1 ? 0.f : pt;
    float c1 = isR1 ? pt : 0.f;
    c0 += ptx;
    #pragma unroll
    for (int off = 32; off > 0; off >>= 1) {
        c0 += __shfl_xor(c0, off);
        c1 += __shfl_xor(c1, off);
    }
    if ((tid & 63) == 0) wreds[w] = make_float2(c0, c1);
    __syncthreads();                           // pS + wreds visible

    // ---- PV (unnormalized), shared x loads, row-0 wave-uniform skip ----
    const int h = tid & 63;
    const int g = w;
    const float* xh = x + b * TLEN * CDIM + h;
    const int nj4 = (rr[1] >> 2) + 1;
    float4 a0 = make_float4(0.f, 0.f, 0.f, 0.f);
    float4 a1 = a0;
    for (int j4 = g; j4 < nj4; j4 += 8) {
        const int j0 = j4 * 4;
        const float4 p1v = ((const float4*)pS[1])[j4];  // LDS broadcast
        const float x0 = xh[j0 * CDIM];                 // coalesced
        const float x1 = xh[(j0 + 1) * CDIM];
        const float x2 = xh[(j0 + 2) * CDIM];
        const float x3 = xh[(j0 + 3) * CDIM];
        a1.x = fmaf(p1v.x, x0, a1.x); a1.y = fmaf(p1v.y, x1, a1.y);
        a1.z = fmaf(p1v.z, x2, a1.z); a1.w = fmaf(p1v.w, x3, a1.w);
        if (j0 <= rr[0]) {                              // wave-uniform
            const float4 p0v = ((const float4*)pS[0])[j4];
            a0.x = fmaf(p0v.x, x0, a0.x); a0.y = fmaf(p0v.y, x1, a0.y);
            a0.z = fmaf(p0v.z, x2, a0.z); a0.w = fmaf(p0v.w, x3, a0.w);
        }
    }
    pvs[0][g][h] = (a0.x + a0.y) + (a0.z + a0.w);
    pvs[1][g][h] = (a1.x + a1.y) + (a1.z + a1.w);
    __syncthreads();
    if (tid < 128) {
        const int k = tid >> 6, hh = tid & 63;
        float o = pvs[k][0][hh];
        #pragma unroll
        for (int ww = 1; ww < 8; ++ww) o += pvs[k][ww][hh];
        float gsum = 0.f;
        #pragma unroll
        for (int ww = 0; ww < 8; ++ww)
            gsum += (k == 0) ? wreds[ww].x : wreds[ww].y;
        o_s[k][hh] = o / gsum;                 // normalization folded here
    }
    __syncthreads();
    if (tid < 128) {                           // out = o_k . Wv[h,:] (LDS)
        const int k = tid >> 6, hh = tid & 63;
        const float4* wb = wv_s + hh * 16;
        const int sw = hh & 15;
        const float4* o4 = (const float4*)o_s[k];
        float4 a = make_float4(0.f, 0.f, 0.f, 0.f);
        #pragma unroll
        for (int c4 = 0; c4 < 16; ++c4) {
            const float4 wwv = wb[c4 ^ sw];
            const float4 oo = o4[c4];
            a.x = fmaf(oo.x, wwv.x, a.x); a.y = fmaf(oo.y, wwv.y, a.y);
            a.z = fmaf(oo.z, wwv.z, a.z); a.w = fmaf(oo.w, wwv.w, a.w);
        }
        out[(b * TLEN + rr[k]) * CDIM + hh] = (a.x + a.y) + (a.z + a.w);
    }
}

extern "C" void kernel_launch(void* const* d_in, const int* in_sizes, int n_in,
                              void* d_out, int out_size, void* d_ws, size_t ws_size,
                              hipStream_t stream)
{
    const float* x   = (const float*)d_in[0];
    const float* pos = (const float*)d_in[1];
    const float* W1  = (const float*)d_in[2];
    const float* b1  = (const float*)d_in[3];
    const float* W2  = (const float*)d_in[4];
    const float* b2  = (const float*)d_in[5];
    const float* Wv  = (const float*)d_in[6];
    float* out = (float*)d_out;

    float4* hkt4 = (float4*)d_ws;              // 256 KiB transposed hk

    hk_kernel<<<BDIM * TLEN / 4, 256, 0, stream>>>(x, pos, W1, hkt4);
    attn_kernel<<<BDIM * TLEN / 2, 512, 0, stream>>>(x, pos, W1, b1, W2, b2, Wv,
                                                     hkt4, out);
}

// Round 20
// 18.724 us; speedup vs baseline: 8.4083x; 1.0186x over previous
//
#include <hip/hip_runtime.h>
#include <math.h>

constexpr int TLEN = 512;
constexpr int CDIM = 64;
constexpr int BDIM = 2;

// Kernel 1: projections (R16's proj, verified). Outputs:
//   hkt4[(b*16+c4)*512 + t] : hk transposed, f4-over-c
//   hqb[(b*512+t)*64 + c]   : hq + b1, row-major
// 256 blocks x 256 threads, 4 rows/block; full W1 (64 KB) staged swizzled.
__global__ __launch_bounds__(256) void proj_kernel(
    const float* __restrict__ x, const float* __restrict__ pos,
    const float* __restrict__ W1, const float* __restrict__ b1,
    float4* __restrict__ hkt4, float* __restrict__ hqb)
{
    const int tid = threadIdx.x;
    const int r0g = blockIdx.x * 4;
    const int b   = r0g >> 9;
    const int t0  = r0g & (TLEN - 1);

    __shared__ float4 w1_s[64 * 64];          // 64 KiB swizzled W1 (Wk|Wq)
    __shared__ alignas(16) float x1s[4][128];
    __shared__ float hks[CDIM][5];            // +1 pad

    const float4* W1f4 = (const float4*)W1;
    #pragma unroll
    for (int m = tid; m < 64 * 64; m += 256) {
        const int c = m >> 6, e4 = m & 63;
        w1_s[c * 64 + (e4 ^ (c & 63))] = W1f4[c * 64 + e4];
    }
    #pragma unroll
    for (int e = tid; e < 4 * 128; e += 256) {
        const int r4 = e >> 7, d = e & 127;
        const int grow = r0g + r4;
        const int tt = grow & (TLEN - 1);
        x1s[r4][d] = (d < CDIM) ? pos[tt * CDIM + d]
                                : x[grow * CDIM + (d - CDIM)];
    }
    __syncthreads();

    {
        const int sub = tid >> 6, c = tid & 63;
        const int grow = r0g + sub;
        const float4* xv = (const float4*)x1s[sub];
        const float4* wb = w1_s + c * 64;
        const int sw = c & 63;
        float4 ak = make_float4(0.f, 0.f, 0.f, 0.f);
        float4 aq = ak;
        #pragma unroll
        for (int d4 = 0; d4 < 32; ++d4) {
            const float4 xx = xv[d4];
            const float4 wk = wb[d4 ^ sw];
            const float4 wq = wb[(32 + d4) ^ sw];
            ak.x = fmaf(xx.x, wk.x, ak.x); ak.y = fmaf(xx.y, wk.y, ak.y);
            ak.z = fmaf(xx.z, wk.z, ak.z); ak.w = fmaf(xx.w, wk.w, ak.w);
            aq.x = fmaf(xx.x, wq.x, aq.x); aq.y = fmaf(xx.y, wq.y, aq.y);
            aq.z = fmaf(xx.z, wq.z, aq.z); aq.w = fmaf(xx.w, wq.w, aq.w);
        }
        hks[c][sub] = (ak.x + ak.y) + (ak.z + ak.w);
        hqb[grow * CDIM + c] = (aq.x + aq.y) + (aq.z + aq.w) + b1[c];
    }
    __syncthreads();

    if (tid < 64) {                            // transpose-store f4 over c
        const int c4 = tid >> 2, tl = tid & 3;
        const float4 v = make_float4(hks[c4 * 4 + 0][tl], hks[c4 * 4 + 1][tl],
                                     hks[c4 * 4 + 2][tl], hks[c4 * 4 + 3][tl]);
        hkt4[(b * 16 + c4) * TLEN + t0 + tl] = v;
    }
}

// Kernel 2: attn = R15's structure (two-pass score, no-max softmax) with the
// hq phase REMOVED (hq precomputed by proj, staged via 32 threads). No Wq
// stage, no x1 stage, 2 fewer barriers, ~25 KB LDS.
__global__ __launch_bounds__(512, 4) void attn_kernel(
    const float* __restrict__ x,   const float* __restrict__ W2,
    const float* __restrict__ b2,  const float* __restrict__ Wv,
    const float4* __restrict__ hkt4, const float4* __restrict__ hqb4,
    float* __restrict__ out)
{
    const int tid = threadIdx.x;
    const int idx = blockIdx.x;               // 0..511
    const int b   = idx & 1;
    const int p   = idx >> 1;                 // 0..255
    int rr[2];
    rr[0] = p; rr[1] = (TLEN - 1) - p;        // rr[1] >= 256 > rr[0]

    __shared__ float4 wv_s[64 * 16];          // 16 KiB swizzled Wv
    __shared__ float4 hq_s[2][16];            // hq+b1 both rows (from proj)
    __shared__ float4 w24_s[16];
    __shared__ alignas(16) float pS[2][TLEN];
    __shared__ float2 wreds[8];               // per-wave exp-sums (2 rows)
    __shared__ float pvs[2][8][CDIM];
    __shared__ alignas(16) float o_s[2][CDIM];

    // ---- stage Wv (swizzled), hq rows, W2 ----
    const float4* Wvf4 = (const float4*)Wv;
    #pragma unroll
    for (int m = tid; m < 64 * 16; m += 512) {
        const int hh = m >> 4, e4 = m & 15;
        wv_s[hh * 16 + (e4 ^ (hh & 15))] = Wvf4[hh * 16 + e4];
    }
    if (tid < 32) {
        const int rp = tid >> 4, e = tid & 15;
        hq_s[rp][e] = hqb4[(b * TLEN + rr[rp]) * 16 + e];
    } else if (tid < 48) {
        w24_s[tid - 32] = ((const float4*)W2)[tid - 32];
    }
    __syncthreads();

    // ---- scores -> exp -> pS + per-wave sums (two-pass, no max; R15) ----
    const float b2v = b2[0];
    const float4* hk4b = hkt4 + b * 16 * TLEN;
    const int j = tid;
    const int w = tid >> 6;

    float swv[2];
    #pragma unroll
    for (int k = 0; k < 2; ++k) {
        const int rk = rr[k];
        if ((w << 6) <= rk) {                 // wave-uniform causal skip
            const float4* hq4 = hq_s[k];
            float4 acc = make_float4(0.f, 0.f, 0.f, 0.f);
            #pragma unroll
            for (int c4 = 0; c4 < 16; ++c4) {
                const float4 kk = hk4b[c4 * TLEN + j];
                const float4 qq = hq4[c4];
                const float4 w2v = w24_s[c4];
                acc.x = fmaf(fmaxf(kk.x + qq.x, 0.f), w2v.x, acc.x);
                acc.y = fmaf(fmaxf(kk.y + qq.y, 0.f), w2v.y, acc.y);
                acc.z = fmaf(fmaxf(kk.z + qq.z, 0.f), w2v.z, acc.z);
                acc.w = fmaf(fmaxf(kk.w + qq.w, 0.f), w2v.w, acc.w);
            }
            const bool vld = (j <= rk);
            const float sv = ((acc.x + acc.y) + (acc.z + acc.w) + b2v) * 0.125f;
            const float pt = vld ? __expf(sv) : 0.f;   // bounded scores
            pS[k][j] = pt;
            float sm = pt;
            #pragma unroll
            for (int off = 32; off > 0; off >>= 1)
                sm += __shfl_xor(sm, off);
            swv[k] = sm;
        } else {
            swv[k] = 0.f;                     // pS beyond rk never read
        }
    }
    if ((tid & 63) == 0) wreds[w] = make_float2(swv[0], swv[1]);
    __syncthreads();                           // pS + wreds visible

    // ---- PV (unnormalized), shared x loads, row-0 wave-uniform skip ----
    const int h = tid & 63;
    const int g = w;
    const float* xh = x + b * TLEN * CDIM + h;
    const int nj4 = (rr[1] >> 2) + 1;
    float4 a0 = make_float4(0.f, 0.f, 0.f, 0.f);
    float4 a1 = a0;
    for (int j4 = g; j4 < nj4; j4 += 8) {
        const int j0 = j4 * 4;
        const float4 p1v = ((const float4*)pS[1])[j4];  // LDS broadcast
        const float x0 = xh[j0 * CDIM];                 // coalesced
        const float x1 = xh[(j0 + 1) * CDIM];
        const float x2 = xh[(j0 + 2) * CDIM];
        const float x3 = xh[(j0 + 3) * CDIM];
        a1.x = fmaf(p1v.x, x0, a1.x); a1.y = fmaf(p1v.y, x1, a1.y);
        a1.z = fmaf(p1v.z, x2, a1.z); a1.w = fmaf(p1v.w, x3, a1.w);
        if (j0 <= rr[0]) {                              // wave-uniform
            const float4 p0v = ((const float4*)pS[0])[j4];
            a0.x = fmaf(p0v.x, x0, a0.x); a0.y = fmaf(p0v.y, x1, a0.y);
            a0.z = fmaf(p0v.z, x2, a0.z); a0.w = fmaf(p0v.w, x3, a0.w);
        }
    }
    pvs[0][g][h] = (a0.x + a0.y) + (a0.z + a0.w);
    pvs[1][g][h] = (a1.x + a1.y) + (a1.z + a1.w);
    __syncthreads();
    if (tid < 128) {
        const int k = tid >> 6, hh = tid & 63;
        float o = pvs[k][0][hh];
        #pragma unroll
        for (int ww = 1; ww < 8; ++ww) o += pvs[k][ww][hh];
        float gsum = 0.f;
        #pragma unroll
        for (int ww = 0; ww < 8; ++ww)
            gsum += (k == 0) ? wreds[ww].x : wreds[ww].y;
        o_s[k][hh] = o / gsum;                 // normalization folded here
    }
    __syncthreads();
    if (tid < 128) {                           // out = o_k . Wv[h,:] (LDS)
        const int k = tid >> 6, hh = tid & 63;
        const float4* wb = wv_s + hh * 16;
        const int sw = hh & 15;
        const float4* o4 = (const float4*)o_s[k];
        float4 a = make_float4(0.f, 0.f, 0.f, 0.f);
        #pragma unroll
        for (int c4 = 0; c4 < 16; ++c4) {
            const float4 wwv = wb[c4 ^ sw];
            const float4 oo = o4[c4];
            a.x = fmaf(oo.x, wwv.x, a.x); a.y = fmaf(oo.y, wwv.y, a.y);
            a.z = fmaf(oo.z, wwv.z, a.z); a.w = fmaf(oo.w, wwv.w, a.w);
        }
        out[(b * TLEN + rr[k]) * CDIM + hh] = (a.x + a.y) + (a.z + a.w);
    }
}

extern "C" void kernel_launch(void* const* d_in, const int* in_sizes, int n_in,
                              void* d_out, int out_size, void* d_ws, size_t ws_size,
                              hipStream_t stream)
{
    const float* x   = (const float*)d_in[0];
    const float* pos = (const float*)d_in[1];
    const float* W1  = (const float*)d_in[2];
    const float* b1  = (const float*)d_in[3];
    const float* W2  = (const float*)d_in[4];
    const float* b2  = (const float*)d_in[5];
    const float* Wv  = (const float*)d_in[6];
    float* out = (float*)d_out;

    float4* hkt4 = (float4*)d_ws;                      // 256 KiB transposed hk
    float*  hqb  = (float*)d_ws + 4 * 16384;           // 256 KiB hq + b1

    proj_kernel<<<BDIM * TLEN / 4, 256, 0, stream>>>(x, pos, W1, b1, hkt4, hqb);
    attn_kernel<<<BDIM * TLEN / 2, 512, 0, stream>>>(x, W2, b2, Wv,
                                                     hkt4, (const float4*)hqb,
                                                     out);
}